// Round 3
// baseline (25569.539 us; speedup 1.0000x reference)
//
#include <hip/hip_runtime.h>
#include <hip/hip_cooperative_groups.h>
#include <stdint.h>

namespace cg = cooperative_groups;

#define NN 8192
#define DD 768
#define LOG2E 1.4426950408889634f

typedef unsigned int  U32;
typedef unsigned short U16;

// monotonic float->uint key for atomicMax on floats
__device__ __forceinline__ U32 fkey(float x){
  U32 u = __float_as_uint(x);
  return (u & 0x80000000u) ? ~u : (u | 0x80000000u);
}
__device__ __forceinline__ float funkey(U32 k){
  return __uint_as_float((k & 0x80000000u) ? (k ^ 0x80000000u) : ~k);
}
__device__ __forceinline__ float ex2(float x){ return __builtin_amdgcn_exp2f(x); }
__device__ __forceinline__ float bflo(U32 w){ return __uint_as_float(w << 16); }
__device__ __forceinline__ float bfhi(U32 w){ return __uint_as_float(w & 0xFFFF0000u); }
// pack two floats to bf16x2 (RNE)
__device__ __forceinline__ U32 packbf(float lo, float hi){
  U32 a = __float_as_uint(lo), b = __float_as_uint(hi);
  a = a + 0x7FFFu + ((a >> 16) & 1u);
  b = b + 0x7FFFu + ((b >> 16) & 1u);
  return (a >> 16) | (b & 0xFFFF0000u);
}

// slots: 0 qmax(u32) 1 qmin(u32) 2 maxsqA key 3 maxsqB key
__global__ __launch_bounds__(64) void k_init(U32* slots){
  if (threadIdx.x == 0){ slots[0]=0u; slots[1]=0xFFFFFFFFu; slots[2]=0u; slots[3]=0u; }
}

__global__ __launch_bounds__(256) void k_sqsum(const float* __restrict__ A, const float* __restrict__ B,
                                               float* sqA, float* sqB, U32* slots){
  int wv = threadIdx.x >> 6, ln = threadIdx.x & 63;
  int row = blockIdx.x*4 + wv;
  const float* src = A; float* dst = sqA; U32* slot = slots + 2; int r = row;
  if (row >= NN){ src = B; dst = sqB; slot = slots + 3; r = row - NN; }
  const float* p = src + (size_t)r * DD;
  float s = 0.f;
  #pragma unroll
  for (int m = 0; m < DD/64; ++m){ float v = p[ln + 64*m]; s = fmaf(v, v, s); }
  #pragma unroll
  for (int o = 32; o; o >>= 1) s += __shfl_xor(s, o);
  if (ln == 0){ dst[r] = s; atomicMax(slot, fkey(s)); }
}

// 128x128 tile fp32 Gram -> dist -> u16 quantize; track qmax/qmin
__global__ __launch_bounds__(256) void k_dist(const float* __restrict__ A, const float* __restrict__ B,
                                              U16* __restrict__ q, const float* __restrict__ sqA,
                                              const float* __restrict__ sqB, U32* slots){
  __shared__ float As[16][128], Bs[16][128];
  __shared__ U32 redmx[4], redmn[4];
  const int t = threadIdx.x;
  const int i0 = blockIdx.y*128, j0 = blockIdx.x*128;
  const float S = 65535.f / (sqrtf(funkey(slots[2])) + sqrtf(funkey(slots[3])));
  float acc[8][8];
  #pragma unroll
  for (int m=0;m<8;m++)
    #pragma unroll
    for (int n=0;n<8;n++) acc[m][n] = 0.f;
  const int lr = t >> 1, lk = (t & 1)*8;
  const float* pa = A + (size_t)(i0+lr)*DD + lk;
  const float* pb = B + (size_t)(j0+lr)*DD + lk;
  const int tx = t & 15, ty = t >> 4;
  for (int k0 = 0; k0 < DD; k0 += 16){
    __syncthreads();
    float4 a0 = *(const float4*)(pa + k0);
    float4 a1 = *(const float4*)(pa + k0 + 4);
    float4 b0 = *(const float4*)(pb + k0);
    float4 b1 = *(const float4*)(pb + k0 + 4);
    As[lk+0][lr]=a0.x; As[lk+1][lr]=a0.y; As[lk+2][lr]=a0.z; As[lk+3][lr]=a0.w;
    As[lk+4][lr]=a1.x; As[lk+5][lr]=a1.y; As[lk+6][lr]=a1.z; As[lk+7][lr]=a1.w;
    Bs[lk+0][lr]=b0.x; Bs[lk+1][lr]=b0.y; Bs[lk+2][lr]=b0.z; Bs[lk+3][lr]=b0.w;
    Bs[lk+4][lr]=b1.x; Bs[lk+5][lr]=b1.y; Bs[lk+6][lr]=b1.z; Bs[lk+7][lr]=b1.w;
    __syncthreads();
    #pragma unroll
    for (int kk = 0; kk < 16; ++kk){
      float4 am0 = *(const float4*)&As[kk][ty*8];
      float4 am1 = *(const float4*)&As[kk][ty*8+4];
      float4 bn0 = *(const float4*)&Bs[kk][tx*8];
      float4 bn1 = *(const float4*)&Bs[kk][tx*8+4];
      float ar[8] = {am0.x,am0.y,am0.z,am0.w,am1.x,am1.y,am1.z,am1.w};
      float br[8] = {bn0.x,bn0.y,bn0.z,bn0.w,bn1.x,bn1.y,bn1.z,bn1.w};
      #pragma unroll
      for (int m=0;m<8;m++)
        #pragma unroll
        for (int n=0;n<8;n++) acc[m][n] = fmaf(ar[m], br[n], acc[m][n]);
    }
  }
  U32 bmax = 0u, bmin = 0xFFFFu;
  #pragma unroll
  for (int m=0;m<8;m++){
    int i = i0 + ty*8 + m;
    float sa = sqA[i];
    U16 pk[8] __attribute__((aligned(16)));
    #pragma unroll
    for (int n=0;n<8;n++){
      int j = j0 + tx*8 + n;
      float sq = sa + sqB[j] - 2.f*acc[m][n];
      float d = sqrtf(fmaxf(sq, 0.f));
      d = fmaxf(d, 1e-6f);
      U32 qv = (U32)rintf(d * S);
      if (qv > 65535u) qv = 65535u;
      bmax = bmax > qv ? bmax : qv;
      bmin = bmin < qv ? bmin : qv;
      pk[n] = (U16)qv;
    }
    *(uint4*)(q + (size_t)i*NN + j0 + tx*8) = *(const uint4*)pk;
  }
  #pragma unroll
  for (int o=32;o;o>>=1){
    U32 om = __shfl_xor(bmax, o); bmax = bmax > om ? bmax : om;
    U32 on = __shfl_xor(bmin, o); bmin = bmin < on ? bmin : on;
  }
  if ((t & 63) == 0){ redmx[t>>6] = bmax; redmn[t>>6] = bmin; }
  __syncthreads();
  if (t == 0){
    U32 mx = redmx[0], mn = redmn[0];
    #pragma unroll
    for (int i=1;i<4;i++){ mx = mx > redmx[i] ? mx : redmx[i]; mn = mn < redmn[i] ? mn : redmn[i]; }
    atomicMax(slots+0, mx); atomicMin(slots+1, mn);
  }
}

// in-place u16 q -> bf16 K' = exp(logK + s), s = 50(1+qmin/qmax) ln-units.
__global__ __launch_bounds__(256) void k_buildK(U32* K2, const U32* __restrict__ slots){
  const float qmaxf = (float)slots[0];
  const float r0n = (float)slots[1] / qmaxf;
  const float k1 = -100.f*LOG2E/qmaxf;
  const float c2 = 50.f*(1.f + r0n)*LOG2E;
  const float tcl = -1e-4f*LOG2E;
  size_t base = ((size_t)blockIdx.x*256 + threadIdx.x)*4;
  uint4 w = *(uint4*)(K2 + base);
  U32 r[4];
  U32 in[4] = {w.x, w.y, w.z, w.w};
  #pragma unroll
  for (int k=0;k<4;++k){
    float ql = (float)(in[k] & 0xFFFFu);
    float qh = (float)(in[k] >> 16);
    float el = ex2(fminf(ql*k1, tcl) + c2);
    float eh = ex2(fminf(qh*k1, tcl) + c2);
    r[k] = packbf(el, eh);
  }
  *(uint4*)(K2 + base) = make_uint4(r[0], r[1], r[2], r[3]);
}

// Whole Sinkhorn loop: 256 blocks x 1024 threads, cooperative.
// Block b owns rows [32b, 32b+32). u lives in LDS across all 200 iterations.
// part = float[256][8192] (in d_out scratch).
__global__ __launch_bounds__(1024) void k_loop(const uint4* __restrict__ Kp,
                                               float* __restrict__ part,
                                               float* __restrict__ v,
                                               float* __restrict__ u){
  cg::grid_group grid = cg::this_grid();
  __shared__ float u_lds[32];
  __shared__ float vl[NN];        // 32 KB
  __shared__ float red[32][33];   // 4.2 KB, bank-safe
  const int t = threadIdx.x;
  const int b = blockIdx.x;
  const int r0 = b*32;
  const int wv = t >> 6, ln = t & 63;
  const int c = t & 31, rr = t >> 5;
  if (t < 32) u_lds[t] = 1.0f/8192.0f;
  __syncthreads();

  for (int it = 0; it < 200; ++it){
    // ---- col partials: part[b][j] = sum_{i<32} K[r0+i][j] * u_lds[i]
    {
      float a[8];
      #pragma unroll
      for (int m=0;m<8;m++) a[m] = 0.f;
      const uint4* p = Kp + (size_t)r0*1024 + t;
      #pragma unroll 8
      for (int i=0;i<32;++i){
        uint4 w = p[(size_t)i*1024];
        float ui = u_lds[i];
        a[0]=fmaf(bflo(w.x),ui,a[0]); a[1]=fmaf(bfhi(w.x),ui,a[1]);
        a[2]=fmaf(bflo(w.y),ui,a[2]); a[3]=fmaf(bfhi(w.y),ui,a[3]);
        a[4]=fmaf(bflo(w.z),ui,a[4]); a[5]=fmaf(bfhi(w.z),ui,a[5]);
        a[6]=fmaf(bflo(w.w),ui,a[6]); a[7]=fmaf(bfhi(w.w),ui,a[7]);
      }
      float* pp = part + (size_t)b*NN + t*8;
      *(float4*)pp     = make_float4(a[0],a[1],a[2],a[3]);
      *(float4*)(pp+4) = make_float4(a[4],a[5],a[6],a[7]);
    }
    grid.sync();
    // ---- reduce: v[b*32+c] = 1 / sum_{chunks} part[chunk][b*32+c]
    {
      float s = 0.f;
      #pragma unroll
      for (int m=0;m<8;++m) s += part[(size_t)(rr + 32*m)*NN + b*32 + c];
      red[rr][c] = s;
      __syncthreads();
      if (t < 32){
        float q2 = red[0][t];
        #pragma unroll
        for (int r2=1;r2<32;++r2) q2 += red[r2][t];
        v[b*32 + t] = 1.0f / q2;
      }
    }
    grid.sync();
    // ---- row pass: u_lds[i] = 1 / sum_j K[r0+i][j] * v[j]
    {
      ((float4*)vl)[t]        = ((const float4*)v)[t];
      ((float4*)vl)[t + 1024] = ((const float4*)v)[t + 1024];
      __syncthreads();
      #pragma unroll
      for (int half=0; half<2; ++half){
        const int row_l = wv + half*16;
        const uint4* p = Kp + (size_t)(r0 + row_l)*1024;
        float s = 0.f;
        #pragma unroll 4
        for (int k=0;k<16;++k){
          uint4 w = p[k*64 + ln];
          const float* vp = &vl[(k*64+ln)*8];
          float4 v0 = *(const float4*)vp;
          float4 v1 = *(const float4*)(vp+4);
          s=fmaf(bflo(w.x),v0.x,s); s=fmaf(bfhi(w.x),v0.y,s);
          s=fmaf(bflo(w.y),v0.z,s); s=fmaf(bfhi(w.y),v0.w,s);
          s=fmaf(bflo(w.z),v1.x,s); s=fmaf(bfhi(w.z),v1.y,s);
          s=fmaf(bflo(w.w),v1.z,s); s=fmaf(bfhi(w.w),v1.w,s);
        }
        #pragma unroll
        for (int o=32;o;o>>=1) s += __shfl_xor(s,o);
        if (ln == 0) u_lds[row_l] = 1.0f / s;
      }
      __syncthreads();
    }
  }
  if (t < 32) u[r0 + t] = u_lds[t];
}

// aligned_A[i][d] = u_i * sum_j K'[i][j] * (v'_j * A[j][d])
__global__ __launch_bounds__(256) void k_outA(const U16* __restrict__ Kp, const float* __restrict__ A,
                                              const float* __restrict__ u, const float* __restrict__ v,
                                              float* __restrict__ outA){
  __shared__ float T[64][64];
  const int t = threadIdx.x;
  const int i0 = blockIdx.y*64, d0 = blockIdx.x*128;
  const int jc = t & 63, ig = t >> 6;
  const int dg = t & 31, ig2 = t >> 5;
  float4 acc[8];
  #pragma unroll
  for (int m=0;m<8;m++) acc[m] = make_float4(0.f,0.f,0.f,0.f);
  for (int j0 = 0; j0 < NN; j0 += 64){
    __syncthreads();
    float vv = v[j0 + jc];
    #pragma unroll
    for (int m=0;m<16;m++){
      int i = i0 + ig*16 + m;
      U32 kb = ((U32)Kp[(size_t)i*NN + j0 + jc]) << 16;
      T[ig*16+m][jc] = __uint_as_float(kb) * vv;
    }
    __syncthreads();
    #pragma unroll 4
    for (int jj = 0; jj < 64; ++jj){
      float4 a4 = *(const float4*)(A + (size_t)(j0+jj)*DD + d0 + dg*4);
      #pragma unroll
      for (int m=0;m<8;m++){
        float tv = T[ig2*8+m][jj];
        acc[m].x = fmaf(tv, a4.x, acc[m].x);
        acc[m].y = fmaf(tv, a4.y, acc[m].y);
        acc[m].z = fmaf(tv, a4.z, acc[m].z);
        acc[m].w = fmaf(tv, a4.w, acc[m].w);
      }
    }
  }
  #pragma unroll
  for (int m=0;m<8;m++){
    int i = i0 + ig2*8 + m;
    float ui = u[i];
    acc[m].x *= ui; acc[m].y *= ui; acc[m].z *= ui; acc[m].w *= ui;
    *(float4*)(outA + (size_t)i*DD + d0 + dg*4) = acc[m];
  }
}

// aligned_B[j][d] = v'_j * sum_i (u_i * K'[i][j]) * B[i][d]
__global__ __launch_bounds__(256) void k_outB(const U16* __restrict__ Kp, const float* __restrict__ B,
                                              const float* __restrict__ u, const float* __restrict__ v,
                                              float* __restrict__ outB){
  __shared__ float Tt[64][65];
  const int t = threadIdx.x;
  const int j0t = blockIdx.y*64, d0 = blockIdx.x*128;
  const int jc = t & 63, ig = t >> 6;
  const int dg = t & 31, jg = t >> 5;
  float4 acc[8];
  #pragma unroll
  for (int m=0;m<8;m++) acc[m] = make_float4(0.f,0.f,0.f,0.f);
  for (int i0 = 0; i0 < NN; i0 += 64){
    __syncthreads();
    #pragma unroll
    for (int m=0;m<16;m++){
      int i = i0 + ig*16 + m;
      U32 kb = ((U32)Kp[(size_t)i*NN + j0t + jc]) << 16;
      Tt[jc][ig*16+m] = __uint_as_float(kb) * u[i];
    }
    __syncthreads();
    #pragma unroll 4
    for (int ii = 0; ii < 64; ++ii){
      float4 b4 = *(const float4*)(B + (size_t)(i0+ii)*DD + d0 + dg*4);
      #pragma unroll
      for (int m=0;m<8;m++){
        float tv = Tt[jg*8+m][ii];
        acc[m].x = fmaf(tv, b4.x, acc[m].x);
        acc[m].y = fmaf(tv, b4.y, acc[m].y);
        acc[m].z = fmaf(tv, b4.z, acc[m].z);
        acc[m].w = fmaf(tv, b4.w, acc[m].w);
      }
    }
  }
  #pragma unroll
  for (int m=0;m<8;m++){
    int j = j0t + jg*8 + m;
    float vj = v[j];
    acc[m].x *= vj; acc[m].y *= vj; acc[m].z *= vj; acc[m].w *= vj;
    *(float4*)(outB + (size_t)j*DD + d0 + dg*4) = acc[m];
  }
}

extern "C" void kernel_launch(void* const* d_in, const int* in_sizes, int n_in,
                              void* d_out, int out_size, void* d_ws, size_t ws_size,
                              hipStream_t stream) {
  const float* A = (const float*)d_in[0];
  const float* B = (const float*)d_in[1];
  float* out = (float*)d_out;
  char* ws = (char*)d_ws;
  // ws layout (same proven envelope as R2); part lives in d_out (free until k_out).
  U16*  q     = (U16*) (ws);                          // 8192*8192*2 = 134217728
  float* u    = (float*)(ws + 136314880);             // 32768
  float* v    = (float*)(ws + 136347648);             // 32768
  float* sqA  = (float*)(ws + 136380416);             // 32768
  float* sqB  = (float*)(ws + 136413184);             // 32768
  U32*  slots = (U32*) (ws + 136445952);              // scalars
  float* part = out;                                  // 256*8192*4 = 8 MB scratch in d_out

  k_init<<<1, 64, 0, stream>>>(slots);
  k_sqsum<<<4096, 256, 0, stream>>>(A, B, sqA, sqB, slots);
  k_dist<<<dim3(64,64), 256, 0, stream>>>(A, B, q, sqA, sqB, slots);
  k_buildK<<<32768, 256, 0, stream>>>((U32*)q, slots);

  const uint4* Kp4 = (const uint4*)q;
  void* args[] = { (void*)&Kp4, (void*)&part, (void*)&v, (void*)&u };
  hipLaunchCooperativeKernel((const void*)k_loop, dim3(256), dim3(1024), args, 0, stream);

  k_outA<<<dim3(6,128), 256, 0, stream>>>(q, A, u, v, out);
  k_outB<<<dim3(6,128), 256, 0, stream>>>(q, B, u, v, out + (size_t)NN*DD);
}